// Round 1
// baseline (568.546 us; speedup 1.0000x reference)
//
#include <hip/hip_runtime.h>
#include <hip/hip_bf16.h>

typedef unsigned short u16;
typedef short bf16x8 __attribute__((ext_vector_type(8)));
typedef float f32x4 __attribute__((ext_vector_type(4)));
typedef unsigned short u16x8 __attribute__((ext_vector_type(8)));

__device__ __forceinline__ u16 f2bf(float f) {
    unsigned u = __float_as_uint(f);
    return (u16)((u + 0x7FFFu + ((u >> 16) & 1u)) >> 16);  // RNE, no NaNs here
}
__device__ __forceinline__ float bf2f(u16 h) {
    return __uint_as_float(((unsigned)h) << 16);
}

// ---------------------------------------------------------------------------
// Elementwise fp32 -> bf16 cast (x). n4 = elements/4.
// ---------------------------------------------------------------------------
__global__ __launch_bounds__(256) void cast_f32_bf16(const float4* __restrict__ src,
                                                     ushort4* __restrict__ dst, int n4) {
    int i = blockIdx.x * 256 + threadIdx.x;
    if (i < n4) {
        float4 v = src[i];
        ushort4 o;
        o.x = f2bf(v.x); o.y = f2bf(v.y); o.z = f2bf(v.z); o.w = f2bf(v.w);
        dst[i] = o;
    }
}

// ---------------------------------------------------------------------------
// 1024x1024 fp32 -> bf16 transpose: Wt[n][k] = W[k][n]
// block (32,8), 32x32 tiles, LDS pad +1 to kill bank conflicts
// ---------------------------------------------------------------------------
__global__ __launch_bounds__(256) void transpose_cast(const float* __restrict__ W,
                                                      u16* __restrict__ Wt) {
    __shared__ float t[32][33];
    int bx = blockIdx.x * 32;  // n
    int by = blockIdx.y * 32;  // k
    int tx = threadIdx.x, ty = threadIdx.y;
    for (int r = ty; r < 32; r += 8)
        t[r][tx] = W[(by + r) * 1024 + bx + tx];
    __syncthreads();
    for (int r = ty; r < 32; r += 8)
        Wt[(long)(bx + r) * 1024 + by + tx] = f2bf(t[tx][r]);
}

// ---------------------------------------------------------------------------
// 128x128-tile bf16 MFMA GEMM, B^T input form: C = A[M,K] * Bt[N,K]^T
// 256 threads = 4 waves (2x2 of 64x64), each wave 4x4 tiles of 16x16x32.
// Staging: global_load_lds width=16, unpadded LDS (lane-order contiguous).
// MODE 0: bf16 out + bias           (Q/K projection)
// MODE 1: bf16 out + bias, store V^T per batch: Vt[b][1024][2048]
// MODE 2: bf16 out, * scale        (scores)
// MODE 3: fp32 out                  (attn @ V -> d_out)
// ---------------------------------------------------------------------------
template <int MODE>
__global__ __launch_bounds__(256)
void gemm_bt(const u16* __restrict__ A, int lda, long sA,
             const u16* __restrict__ Bt, int ldb, long sB,
             const float* __restrict__ bias,
             void* __restrict__ Cout, int ldc, long sC,
             int Kdim, float scale)
{
    __shared__ __align__(16) u16 As[128 * 32];
    __shared__ __align__(16) u16 Bs[128 * 32];
    const int tid  = threadIdx.x;
    const int wave = tid >> 6;
    const int lane = tid & 63;
    const int quad = lane >> 4;
    const int m16  = lane & 15;
    const int bz   = blockIdx.z;
    const u16* Ab = A + (long)bz * sA;
    const u16* Bb = Bt + (long)bz * sB;
    const int row0 = blockIdx.y * 128;
    const int col0 = blockIdx.x * 128;
    const int wr = (wave & 1) * 64;
    const int wc = (wave >> 1) * 64;

    f32x4 acc[4][4] = {};

    for (int k0 = 0; k0 < Kdim; k0 += 32) {
        // stage A-tile (128x32) and B-tile (128x32): 512 16B-chunks each,
        // 2 chunks/thread/tile. LDS chunk index == c so dest = base + lane*16.
#pragma unroll
        for (int it = 0; it < 2; ++it) {
            int c = it * 256 + tid;
            int r = c >> 2, kc = c & 3;
            const u16* ga = Ab + (long)(row0 + r) * lda + (k0 + kc * 8);
            __builtin_amdgcn_global_load_lds(
                (const __attribute__((address_space(1))) void*)ga,
                (__attribute__((address_space(3))) void*)(&As[c * 8]), 16, 0, 0);
            const u16* gb = Bb + (long)(col0 + r) * ldb + (k0 + kc * 8);
            __builtin_amdgcn_global_load_lds(
                (const __attribute__((address_space(1))) void*)gb,
                (__attribute__((address_space(3))) void*)(&Bs[c * 8]), 16, 0, 0);
        }
        __syncthreads();
        bf16x8 af[4], bfr[4];
#pragma unroll
        for (int i = 0; i < 4; ++i)
            af[i] = *(const bf16x8*)&As[(wr + i * 16 + m16) * 32 + quad * 8];
#pragma unroll
        for (int j = 0; j < 4; ++j)
            bfr[j] = *(const bf16x8*)&Bs[(wc + j * 16 + m16) * 32 + quad * 8];
#pragma unroll
        for (int i = 0; i < 4; ++i)
#pragma unroll
            for (int j = 0; j < 4; ++j)
                acc[i][j] = __builtin_amdgcn_mfma_f32_16x16x32_bf16(af[i], bfr[j], acc[i][j], 0, 0, 0);
        __syncthreads();
    }

    // epilogue: C/D layout col=lane&15, row=quad*4+reg (m89/m91-verified)
#pragma unroll
    for (int i = 0; i < 4; ++i) {
#pragma unroll
        for (int j = 0; j < 4; ++j) {
            int col = col0 + wc + j * 16 + m16;
            float badd = (MODE == 0 || MODE == 1) ? bias[col] : 0.0f;
#pragma unroll
            for (int r = 0; r < 4; ++r) {
                int row = row0 + wr + i * 16 + quad * 4 + r;
                float v = acc[i][j][r];
                if (MODE == 0) {
                    ((u16*)Cout)[(long)row * ldc + col] = f2bf(v + badd);
                } else if (MODE == 1) {
                    int b = row >> 11, m = row & 2047;   // batch, key index
                    ((u16*)Cout)[((long)b << 21) + ((long)col << 11) + m] = f2bf(v + badd);
                } else if (MODE == 2) {
                    ((u16*)Cout)[(long)bz * sC + (long)row * ldc + col] = f2bf(v * scale);
                } else {
                    ((float*)Cout)[(long)bz * sC + (long)row * ldc + col] = v;
                }
            }
        }
    }
}

// ---------------------------------------------------------------------------
// In-place row softmax over bf16 [16384 rows][2048], one block per row.
// ---------------------------------------------------------------------------
__global__ __launch_bounds__(256) void softmax_rows(u16* __restrict__ S) {
    __shared__ float red[4];
    const long row = blockIdx.x;
    u16* p = S + row * 2048;
    const int tid = threadIdx.x;
    const int lane = tid & 63, wv = tid >> 6;

    u16x8 raw = *(const u16x8*)(p + tid * 8);
    float v[8];
#pragma unroll
    for (int i = 0; i < 8; ++i) v[i] = bf2f(raw[i]);

    float m = -1e30f;
#pragma unroll
    for (int i = 0; i < 8; ++i) m = fmaxf(m, v[i]);
    for (int off = 32; off > 0; off >>= 1) m = fmaxf(m, __shfl_down(m, off));
    if (lane == 0) red[wv] = m;
    __syncthreads();
    m = fmaxf(fmaxf(red[0], red[1]), fmaxf(red[2], red[3]));

    float s = 0.0f;
#pragma unroll
    for (int i = 0; i < 8; ++i) { v[i] = __expf(v[i] - m); s += v[i]; }
    for (int off = 32; off > 0; off >>= 1) s += __shfl_down(s, off);
    __syncthreads();
    if (lane == 0) red[wv] = s;
    __syncthreads();
    s = red[0] + red[1] + red[2] + red[3];
    float inv = 1.0f / s;

    u16x8 o;
#pragma unroll
    for (int i = 0; i < 8; ++i) o[i] = f2bf(v[i] * inv);
    *(u16x8*)(p + tid * 8) = o;
}

// ---------------------------------------------------------------------------
extern "C" void kernel_launch(void* const* d_in, const int* in_sizes, int n_in,
                              void* d_out, int out_size, void* d_ws, size_t ws_size,
                              hipStream_t stream) {
    const float* x  = (const float*)d_in[0];
    const float* Wq = (const float*)d_in[1];
    const float* bq = (const float*)d_in[2];
    const float* Wk = (const float*)d_in[3];
    const float* bk = (const float*)d_in[4];
    const float* Wv = (const float*)d_in[5];
    const float* bv = (const float*)d_in[6];
    float* out = (float*)d_out;

    // workspace layout (bytes)
    char* ws = (char*)d_ws;
    u16* xb  = (u16*)(ws);                       // 16384x1024 bf16   = 32 MiB
    u16* Wqt = (u16*)(ws + 33554432);            // 1024x1024 bf16    =  2 MiB
    u16* Wkt = (u16*)(ws + 35651584);
    u16* Wvt = (u16*)(ws + 37748736);
    u16* Q   = (u16*)(ws + 39845888);            // 16384x1024 bf16   = 32 MiB
    u16* K   = (u16*)(ws + 73400320);            // 16384x1024 bf16   = 32 MiB
    u16* Vt  = (u16*)(ws + 106954752);           // 8 x 1024x2048 bf16= 32 MiB
    u16* S   = (u16*)(ws + 140509184);           // 8 x 2048x2048 bf16= 64 MiB
    // total 207,618,048 bytes

    // 1) casts
    cast_f32_bf16<<<16384, 256, 0, stream>>>((const float4*)x, (ushort4*)xb, 4194304);
    dim3 tg(32, 32), tb(32, 8);
    transpose_cast<<<tg, tb, 0, stream>>>(Wq, Wqt);
    transpose_cast<<<tg, tb, 0, stream>>>(Wk, Wkt);
    transpose_cast<<<tg, tb, 0, stream>>>(Wv, Wvt);

    // 2) QKV projections: [16384,1024] = xb @ W + b
    dim3 gp(8, 128, 1);
    gemm_bt<0><<<gp, 256, 0, stream>>>(xb, 1024, 0, Wqt, 1024, 0, bq, Q, 1024, 0, 1024, 1.0f);
    gemm_bt<0><<<gp, 256, 0, stream>>>(xb, 1024, 0, Wkt, 1024, 0, bk, K, 1024, 0, 1024, 1.0f);
    gemm_bt<1><<<gp, 256, 0, stream>>>(xb, 1024, 0, Wvt, 1024, 0, bv, Vt, 0, 0, 1024, 1.0f);

    // 3) scores S[b] = (Q[b] @ K[b]^T) / 32, bf16
    dim3 gs(16, 16, 8);
    gemm_bt<2><<<gs, 256, 0, stream>>>(Q, 1024, 2048L * 1024, K, 1024, 2048L * 1024,
                                       nullptr, S, 2048, 2048L * 2048, 1024, 0.03125f);

    // 4) row softmax in place
    softmax_rows<<<16384, 256, 0, stream>>>(S);

    // 5) out[b] = P[b] @ V[b]   (via Vt, fp32 out)
    dim3 gv(8, 16, 8);
    gemm_bt<3><<<gv, 256, 0, stream>>>(S, 2048, 2048L * 2048, Vt, 2048, 1024L * 2048,
                                       nullptr, out, 1024, 2048L * 1024, 2048, 1.0f);
}

// Round 2
// 527.169 us; speedup vs baseline: 1.0785x; 1.0785x over previous
//
#include <hip/hip_runtime.h>
#include <hip/hip_bf16.h>

typedef unsigned short u16;
typedef short bf16x8 __attribute__((ext_vector_type(8)));
typedef float f32x4 __attribute__((ext_vector_type(4)));
typedef unsigned short u16x8 __attribute__((ext_vector_type(8)));
typedef unsigned short u16x4 __attribute__((ext_vector_type(4)));

__device__ __forceinline__ u16 f2bf(float f) {
    unsigned u = __float_as_uint(f);
    return (u16)((u + 0x7FFFu + ((u >> 16) & 1u)) >> 16);  // RNE, no NaNs here
}
__device__ __forceinline__ float bf2f(u16 h) {
    return __uint_as_float(((unsigned)h) << 16);
}

// ---------------------------------------------------------------------------
// Elementwise fp32 -> bf16 cast (x). n4 = elements/4.
// ---------------------------------------------------------------------------
__global__ __launch_bounds__(256) void cast_f32_bf16(const float4* __restrict__ src,
                                                     ushort4* __restrict__ dst, int n4) {
    int i = blockIdx.x * 256 + threadIdx.x;
    if (i < n4) {
        float4 v = src[i];
        ushort4 o;
        o.x = f2bf(v.x); o.y = f2bf(v.y); o.z = f2bf(v.z); o.w = f2bf(v.w);
        dst[i] = o;
    }
}

// ---------------------------------------------------------------------------
// 1024x1024 fp32 -> bf16 transpose: Wt[n][k] = W[k][n]
// ---------------------------------------------------------------------------
__global__ __launch_bounds__(256) void transpose_cast(const float* __restrict__ W,
                                                      u16* __restrict__ Wt) {
    __shared__ float t[32][33];
    int bx = blockIdx.x * 32;  // n
    int by = blockIdx.y * 32;  // k
    int tx = threadIdx.x, ty = threadIdx.y;
    for (int r = ty; r < 32; r += 8)
        t[r][tx] = W[(by + r) * 1024 + bx + tx];
    __syncthreads();
    for (int r = ty; r < 32; r += 8)
        Wt[(long)(bx + r) * 1024 + by + tx] = f2bf(t[tx][r]);
}

// ---------------------------------------------------------------------------
// 128x128-tile bf16 MFMA GEMM, B^T input form: C = A[M,K] * Bt[N,K]^T
// 256 threads = 4 waves (2x2 of 64x64), each wave 4x4 tiles of 16x16x32.
// XCD-aware swizzle: flat%8 -> XCD, each XCD gets a contiguous tile span.
// MODE 0: fused QKV projection. cols<2048 -> bf16+bias into QK[16384][2048];
//         cols>=2048 -> bf16+bias TRANSPOSED into Vt[b][1024][2048] (u16x4 packs
//         4 consecutive rows -> 8B stores instead of 2B scatter).
// MODE 2: bf16 out * scale (scores)
// MODE 3: fp32 out (attn @ V -> d_out)
// ---------------------------------------------------------------------------
template <int MODE>
__global__ __launch_bounds__(256)
void gemm_bt(const u16* __restrict__ A, int lda, long sA,
             const u16* __restrict__ Bt, int ldb, long sB,
             const float* __restrict__ bq_, const float* __restrict__ bk_,
             const float* __restrict__ bv_,
             void* __restrict__ Cout, void* __restrict__ Cout2,
             int ldc, long sC, int Kdim, float scale)
{
    __shared__ __align__(16) u16 As[128 * 32];
    __shared__ __align__(16) u16 Bs[128 * 32];
    const int tid  = threadIdx.x;
    const int wave = tid >> 6;
    const int lane = tid & 63;
    const int quad = lane >> 4;
    const int m16  = lane & 15;

    // XCD swizzle: flat dispatch order round-robins XCDs; give each XCD a
    // contiguous span of tiles (row-panel L2 locality).
    const int gx = gridDim.x, gy = gridDim.y;
    int flat = (blockIdx.z * gy + blockIdx.y) * gx + blockIdx.x;
    int total = gx * gy * gridDim.z;
    int tile = (flat & 7) * (total >> 3) + (flat >> 3);
    const int bx = tile % gx;
    const int by = (tile / gx) % gy;
    const int bz = tile / (gx * gy);

    const u16* Ab = A + (long)bz * sA;
    const u16* Bb = Bt + (long)bz * sB;
    const int row0 = by * 128;
    const int col0 = bx * 128;
    const int wr = (wave & 1) * 64;
    const int wc = (wave >> 1) * 64;

    f32x4 acc[4][4] = {};

    for (int k0 = 0; k0 < Kdim; k0 += 32) {
#pragma unroll
        for (int it = 0; it < 2; ++it) {
            int c = it * 256 + tid;
            int r = c >> 2, kc = c & 3;
            const u16* ga = Ab + (long)(row0 + r) * lda + (k0 + kc * 8);
            __builtin_amdgcn_global_load_lds(
                (const __attribute__((address_space(1))) void*)ga,
                (__attribute__((address_space(3))) void*)(&As[c * 8]), 16, 0, 0);
            const u16* gb = Bb + (long)(col0 + r) * ldb + (k0 + kc * 8);
            __builtin_amdgcn_global_load_lds(
                (const __attribute__((address_space(1))) void*)gb,
                (__attribute__((address_space(3))) void*)(&Bs[c * 8]), 16, 0, 0);
        }
        __syncthreads();
        bf16x8 af[4], bfr[4];
#pragma unroll
        for (int i = 0; i < 4; ++i)
            af[i] = *(const bf16x8*)&As[(wr + i * 16 + m16) * 32 + quad * 8];
#pragma unroll
        for (int j = 0; j < 4; ++j)
            bfr[j] = *(const bf16x8*)&Bs[(wc + j * 16 + m16) * 32 + quad * 8];
#pragma unroll
        for (int i = 0; i < 4; ++i)
#pragma unroll
            for (int j = 0; j < 4; ++j)
                acc[i][j] = __builtin_amdgcn_mfma_f32_16x16x32_bf16(af[i], bfr[j], acc[i][j], 0, 0, 0);
        __syncthreads();
    }

    // epilogue: C/D layout col=lane&15, row=quad*4+reg (m89/m91-verified)
    if (MODE == 0) {
        if (col0 < 2048) {
            const float* bp = (col0 < 1024) ? bq_ : bk_;
#pragma unroll
            for (int i = 0; i < 4; ++i) {
#pragma unroll
                for (int j = 0; j < 4; ++j) {
                    int col = col0 + wc + j * 16 + m16;
                    float badd = bp[col & 1023];
#pragma unroll
                    for (int r = 0; r < 4; ++r) {
                        int row = row0 + wr + i * 16 + quad * 4 + r;
                        ((u16*)Cout)[(long)row * 2048 + col] = f2bf(acc[i][j][r] + badd);
                    }
                }
            }
        } else {
            // V part: store transposed into Vt[b][1024][2048], pack 4 rows/lane
#pragma unroll
            for (int i = 0; i < 4; ++i) {
                int rowb = row0 + wr + i * 16 + quad * 4;
                int b = rowb >> 11, m = rowb & 2047;
#pragma unroll
                for (int j = 0; j < 4; ++j) {
                    int d = col0 + wc + j * 16 + m16 - 2048;
                    float badd = bv_[d];
                    u16x4 pk;
#pragma unroll
                    for (int r = 0; r < 4; ++r) pk[r] = f2bf(acc[i][j][r] + badd);
                    *(u16x4*)((u16*)Cout2 + ((long)b << 21) + ((long)d << 11) + m) = pk;
                }
            }
        }
    } else {
#pragma unroll
        for (int i = 0; i < 4; ++i) {
#pragma unroll
            for (int j = 0; j < 4; ++j) {
                int col = col0 + wc + j * 16 + m16;
#pragma unroll
                for (int r = 0; r < 4; ++r) {
                    int row = row0 + wr + i * 16 + quad * 4 + r;
                    float v = acc[i][j][r];
                    if (MODE == 2) {
                        ((u16*)Cout)[(long)bz * sC + (long)row * ldc + col] = f2bf(v * scale);
                    } else {
                        ((float*)Cout)[(long)bz * sC + (long)row * ldc + col] = v;
                    }
                }
            }
        }
    }
}

// ---------------------------------------------------------------------------
// In-place row softmax over bf16 [16384 rows][2048], one block per row.
// ---------------------------------------------------------------------------
__global__ __launch_bounds__(256) void softmax_rows(u16* __restrict__ S) {
    __shared__ float red[4];
    const long row = blockIdx.x;
    u16* p = S + row * 2048;
    const int tid = threadIdx.x;
    const int lane = tid & 63, wv = tid >> 6;

    u16x8 raw = *(const u16x8*)(p + tid * 8);
    float v[8];
#pragma unroll
    for (int i = 0; i < 8; ++i) v[i] = bf2f(raw[i]);

    float m = -1e30f;
#pragma unroll
    for (int i = 0; i < 8; ++i) m = fmaxf(m, v[i]);
    for (int off = 32; off > 0; off >>= 1) m = fmaxf(m, __shfl_down(m, off));
    if (lane == 0) red[wv] = m;
    __syncthreads();
    m = fmaxf(fmaxf(red[0], red[1]), fmaxf(red[2], red[3]));

    float s = 0.0f;
#pragma unroll
    for (int i = 0; i < 8; ++i) { v[i] = __expf(v[i] - m); s += v[i]; }
    for (int off = 32; off > 0; off >>= 1) s += __shfl_down(s, off);
    __syncthreads();
    if (lane == 0) red[wv] = s;
    __syncthreads();
    s = red[0] + red[1] + red[2] + red[3];
    float inv = 1.0f / s;

    u16x8 o;
#pragma unroll
    for (int i = 0; i < 8; ++i) o[i] = f2bf(v[i] * inv);
    *(u16x8*)(p + tid * 8) = o;
}

// ---------------------------------------------------------------------------
extern "C" void kernel_launch(void* const* d_in, const int* in_sizes, int n_in,
                              void* d_out, int out_size, void* d_ws, size_t ws_size,
                              hipStream_t stream) {
    const float* x  = (const float*)d_in[0];
    const float* Wq = (const float*)d_in[1];
    const float* bq = (const float*)d_in[2];
    const float* Wk = (const float*)d_in[3];
    const float* bk = (const float*)d_in[4];
    const float* Wv = (const float*)d_in[5];
    const float* bv = (const float*)d_in[6];
    float* out = (float*)d_out;

    // workspace layout (bytes)
    char* ws = (char*)d_ws;
    u16* xb = (u16*)(ws);                        // 16384x1024 bf16   = 32 MiB
    u16* WT = (u16*)(ws + 33554432);             // 3072x1024 bf16    =  6 MiB
    u16* QK = (u16*)(ws + 39845888);             // 16384x2048 bf16   = 64 MiB
    u16* Vt = (u16*)(ws + 106954752);            // 8 x 1024x2048 bf16= 32 MiB
    u16* S  = (u16*)(ws + 140509184);            // 8 x 2048x2048 bf16= 64 MiB
    // total 207,618,048 bytes

    // 1) casts
    cast_f32_bf16<<<16384, 256, 0, stream>>>((const float4*)x, (ushort4*)xb, 4194304);
    dim3 tg(32, 32), tb(32, 8);
    transpose_cast<<<tg, tb, 0, stream>>>(Wq, WT);
    transpose_cast<<<tg, tb, 0, stream>>>(Wk, WT + 1048576);
    transpose_cast<<<tg, tb, 0, stream>>>(Wv, WT + 2097152);

    // 2) fused QKV projection: [16384,3072] = xb @ WT^T + b
    dim3 gp(24, 128, 1);
    gemm_bt<0><<<gp, 256, 0, stream>>>(xb, 1024, 0, WT, 1024, 0,
                                       bq, bk, bv, QK, Vt, 0, 0, 1024, 1.0f);

    // 3) scores S[b] = (Q[b] @ K[b]^T) / 32, bf16
    dim3 gs(16, 16, 8);
    gemm_bt<2><<<gs, 256, 0, stream>>>(QK, 2048, 2048L * 2048, QK + 1024, 2048, 2048L * 2048,
                                       nullptr, nullptr, nullptr, S, nullptr,
                                       2048, 2048L * 2048, 1024, 0.03125f);

    // 4) row softmax in place
    softmax_rows<<<16384, 256, 0, stream>>>(S);

    // 5) out[b] = P[b] @ V[b]   (via Vt, fp32 out)
    dim3 gv(8, 16, 8);
    gemm_bt<3><<<gv, 256, 0, stream>>>(S, 2048, 2048L * 2048, Vt, 2048, 1024L * 2048,
                                       nullptr, nullptr, nullptr, out, nullptr,
                                       1024, 2048L * 1024, 2048, 1.0f);
}

// Round 3
// 473.649 us; speedup vs baseline: 1.2004x; 1.1130x over previous
//
#include <hip/hip_runtime.h>
#include <hip/hip_bf16.h>

typedef unsigned short u16;
typedef short bf16x8 __attribute__((ext_vector_type(8)));
typedef float f32x16 __attribute__((ext_vector_type(16)));
typedef unsigned short u16x8 __attribute__((ext_vector_type(8)));
typedef unsigned short u16x4 __attribute__((ext_vector_type(4)));

__device__ __forceinline__ u16 f2bf(float f) {
    unsigned u = __float_as_uint(f);
    return (u16)((u + 0x7FFFu + ((u >> 16) & 1u)) >> 16);  // RNE, no NaNs here
}
__device__ __forceinline__ float bf2f(u16 h) {
    return __uint_as_float(((unsigned)h) << 16);
}

// ---------------------------------------------------------------------------
// Elementwise fp32 -> bf16 cast (x). n4 = elements/4.
// ---------------------------------------------------------------------------
__global__ __launch_bounds__(256) void cast_f32_bf16(const float4* __restrict__ src,
                                                     ushort4* __restrict__ dst, int n4) {
    int i = blockIdx.x * 256 + threadIdx.x;
    if (i < n4) {
        float4 v = src[i];
        ushort4 o;
        o.x = f2bf(v.x); o.y = f2bf(v.y); o.z = f2bf(v.z); o.w = f2bf(v.w);
        dst[i] = o;
    }
}

// ---------------------------------------------------------------------------
// 1024x1024 fp32 -> bf16 transpose: Wt[n][k] = W[k][n]
// ---------------------------------------------------------------------------
__global__ __launch_bounds__(256) void transpose_cast(const float* __restrict__ W,
                                                      u16* __restrict__ Wt) {
    __shared__ float t[32][33];
    int bx = blockIdx.x * 32;  // n
    int by = blockIdx.y * 32;  // k
    int tx = threadIdx.x, ty = threadIdx.y;
    for (int r = ty; r < 32; r += 8)
        t[r][tx] = W[(by + r) * 1024 + bx + tx];
    __syncthreads();
    for (int r = ty; r < 32; r += 8)
        Wt[(long)(bx + r) * 1024 + by + tx] = f2bf(t[tx][r]);
}

// ---------------------------------------------------------------------------
// 128x128-tile bf16 MFMA GEMM, B^T input form: C = A[M,K] * Bt[N,K]^T
// 256 threads = 4 waves (2x2 of 64x64), each wave 2x2 tiles of 32x32x16.
// LDS bank swizzle: chunk kc of row r stored at slot kc ^ ((r>>1)&3) so
// fragment reads spread 2 lanes/bank per quarter-wave (free) instead of 8-way.
// Staging stays coalesced (permutation is within each row's 64B line).
// MODE 0: fused QKV projection. cols<2048 -> bf16+bias into QK[16384][2048];
//         cols>=2048 -> bf16+bias TRANSPOSED into Vt[b][1024][2048].
// MODE 2: bf16 out * scale (scores)
// MODE 3: fp32 out (attn @ V -> d_out)
// ---------------------------------------------------------------------------
template <int MODE>
__global__ __launch_bounds__(256)
void gemm_bt(const u16* __restrict__ A, int lda, long sA,
             const u16* __restrict__ Bt, int ldb, long sB,
             const float* __restrict__ bq_, const float* __restrict__ bk_,
             const float* __restrict__ bv_,
             void* __restrict__ Cout, void* __restrict__ Cout2,
             int ldc, long sC, int Kdim, float scale)
{
    __shared__ __align__(16) u16 As[128 * 32];
    __shared__ __align__(16) u16 Bs[128 * 32];
    const int tid  = threadIdx.x;
    const int wave = tid >> 6;
    const int lane = tid & 63;
    const int m32  = lane & 31;
    const int hi   = lane >> 5;

    // XCD swizzle: flat%8 -> XCD; give each XCD a contiguous tile span.
    const int gx = gridDim.x, gy = gridDim.y;
    int flat = (blockIdx.z * gy + blockIdx.y) * gx + blockIdx.x;
    int total = gx * gy * gridDim.z;
    int tile = (flat & 7) * (total >> 3) + (flat >> 3);
    const int bx = tile % gx;
    const int by = (tile / gx) % gy;
    const int bz = tile / (gx * gy);

    const u16* Ab = A + (long)bz * sA;
    const u16* Bb = Bt + (long)bz * sB;
    const int row0 = by * 128;
    const int col0 = bx * 128;
    const int wr = (wave & 1) * 64;
    const int wc = (wave >> 1) * 64;

    f32x16 acc[2][2] = {};

    // per-lane LDS fragment rows and their swizzle keys
    int arow[2], brow[2], asw[2], bsw[2];
#pragma unroll
    for (int t = 0; t < 2; ++t) {
        arow[t] = wr + t * 32 + m32;
        brow[t] = wc + t * 32 + m32;
        asw[t] = (arow[t] >> 1) & 3;
        bsw[t] = (brow[t] >> 1) & 3;
    }

    for (int k0 = 0; k0 < Kdim; k0 += 32) {
#pragma unroll
        for (int it = 0; it < 2; ++it) {
            int c = it * 256 + tid;
            int r = c >> 2;
            int kc = (c & 3) ^ ((c >> 3) & 3);   // bank swizzle
            const u16* ga = Ab + (long)(row0 + r) * lda + (k0 + kc * 8);
            __builtin_amdgcn_global_load_lds(
                (const __attribute__((address_space(1))) void*)ga,
                (__attribute__((address_space(3))) void*)(&As[c * 8]), 16, 0, 0);
            const u16* gb = Bb + (long)(col0 + r) * ldb + (k0 + kc * 8);
            __builtin_amdgcn_global_load_lds(
                (const __attribute__((address_space(1))) void*)gb,
                (__attribute__((address_space(3))) void*)(&Bs[c * 8]), 16, 0, 0);
        }
        __syncthreads();
        // fragment layout: A[m=lane&31][k=(lane>>5)*8+j]; chunk q = kh*2+hi
        bf16x8 af[2][2], bfr[2][2];  // [kh][tile]
#pragma unroll
        for (int kh = 0; kh < 2; ++kh)
#pragma unroll
            for (int t = 0; t < 2; ++t) {
                int qa = (kh * 2 + hi) ^ asw[t];
                int qb = (kh * 2 + hi) ^ bsw[t];
                af[kh][t]  = *(const bf16x8*)&As[arow[t] * 32 + qa * 8];
                bfr[kh][t] = *(const bf16x8*)&Bs[brow[t] * 32 + qb * 8];
            }
#pragma unroll
        for (int kh = 0; kh < 2; ++kh)
#pragma unroll
            for (int i = 0; i < 2; ++i)
#pragma unroll
                for (int j = 0; j < 2; ++j)
                    acc[i][j] = __builtin_amdgcn_mfma_f32_32x32x16_bf16(
                        af[kh][i], bfr[kh][j], acc[i][j], 0, 0, 0);
        __syncthreads();
    }

    // epilogue: 32x32 C/D layout col=lane&31, row=(reg&3)+8*(reg>>2)+4*(lane>>5)
    if (MODE == 0) {
        if (col0 < 2048) {
            const float* bp = (col0 < 1024) ? bq_ : bk_;
#pragma unroll
            for (int i = 0; i < 2; ++i) {
#pragma unroll
                for (int j = 0; j < 2; ++j) {
                    int col = col0 + wc + j * 32 + m32;
                    float badd = bp[col & 1023];
#pragma unroll
                    for (int g = 0; g < 4; ++g) {
                        int rbase = row0 + wr + i * 32 + 4 * hi + 8 * g;
#pragma unroll
                        for (int rr = 0; rr < 4; ++rr)
                            ((u16*)Cout)[(long)(rbase + rr) * 2048 + col] =
                                f2bf(acc[i][j][g * 4 + rr] + badd);
                    }
                }
            }
        } else {
            // V part: store transposed into Vt[b][1024][2048], 4 rows packed
#pragma unroll
            for (int i = 0; i < 2; ++i) {
#pragma unroll
                for (int j = 0; j < 2; ++j) {
                    int d = col0 + wc + j * 32 + m32 - 2048;
                    float badd = bv_[d];
#pragma unroll
                    for (int g = 0; g < 4; ++g) {
                        int rbase = row0 + wr + i * 32 + 4 * hi + 8 * g;
                        int b = rbase >> 11, m = rbase & 2047;
                        u16x4 pk;
#pragma unroll
                        for (int rr = 0; rr < 4; ++rr)
                            pk[rr] = f2bf(acc[i][j][g * 4 + rr] + badd);
                        *(u16x4*)((u16*)Cout2 + ((long)b << 21) + ((long)d << 11) + m) = pk;
                    }
                }
            }
        }
    } else {
#pragma unroll
        for (int i = 0; i < 2; ++i) {
#pragma unroll
            for (int j = 0; j < 2; ++j) {
                int col = col0 + wc + j * 32 + m32;
#pragma unroll
                for (int g = 0; g < 4; ++g) {
                    int rbase = row0 + wr + i * 32 + 4 * hi + 8 * g;
#pragma unroll
                    for (int rr = 0; rr < 4; ++rr) {
                        int row = rbase + rr;
                        float v = acc[i][j][g * 4 + rr];
                        if (MODE == 2) {
                            ((u16*)Cout)[(long)bz * sC + (long)row * ldc + col] = f2bf(v * scale);
                        } else {
                            ((float*)Cout)[(long)bz * sC + (long)row * ldc + col] = v;
                        }
                    }
                }
            }
        }
    }
}

// ---------------------------------------------------------------------------
// In-place row softmax over bf16 [16384 rows][2048], one block per row.
// ---------------------------------------------------------------------------
__global__ __launch_bounds__(256) void softmax_rows(u16* __restrict__ S) {
    __shared__ float red[4];
    const long row = blockIdx.x;
    u16* p = S + row * 2048;
    const int tid = threadIdx.x;
    const int lane = tid & 63, wv = tid >> 6;

    u16x8 raw = *(const u16x8*)(p + tid * 8);
    float v[8];
#pragma unroll
    for (int i = 0; i < 8; ++i) v[i] = bf2f(raw[i]);

    float m = -1e30f;
#pragma unroll
    for (int i = 0; i < 8; ++i) m = fmaxf(m, v[i]);
    for (int off = 32; off > 0; off >>= 1) m = fmaxf(m, __shfl_down(m, off));
    if (lane == 0) red[wv] = m;
    __syncthreads();
    m = fmaxf(fmaxf(red[0], red[1]), fmaxf(red[2], red[3]));

    float s = 0.0f;
#pragma unroll
    for (int i = 0; i < 8; ++i) { v[i] = __expf(v[i] - m); s += v[i]; }
    for (int off = 32; off > 0; off >>= 1) s += __shfl_down(s, off);
    __syncthreads();
    if (lane == 0) red[wv] = s;
    __syncthreads();
    s = red[0] + red[1] + red[2] + red[3];
    float inv = 1.0f / s;

    u16x8 o;
#pragma unroll
    for (int i = 0; i < 8; ++i) o[i] = f2bf(v[i] * inv);
    *(u16x8*)(p + tid * 8) = o;
}

// ---------------------------------------------------------------------------
extern "C" void kernel_launch(void* const* d_in, const int* in_sizes, int n_in,
                              void* d_out, int out_size, void* d_ws, size_t ws_size,
                              hipStream_t stream) {
    const float* x  = (const float*)d_in[0];
    const float* Wq = (const float*)d_in[1];
    const float* bq = (const float*)d_in[2];
    const float* Wk = (const float*)d_in[3];
    const float* bk = (const float*)d_in[4];
    const float* Wv = (const float*)d_in[5];
    const float* bv = (const float*)d_in[6];
    float* out = (float*)d_out;

    // workspace layout (bytes)
    char* ws = (char*)d_ws;
    u16* xb = (u16*)(ws);                        // 16384x1024 bf16   = 32 MiB
    u16* WT = (u16*)(ws + 33554432);             // 3072x1024 bf16    =  6 MiB
    u16* QK = (u16*)(ws + 39845888);             // 16384x2048 bf16   = 64 MiB
    u16* Vt = (u16*)(ws + 106954752);            // 8 x 1024x2048 bf16= 32 MiB
    u16* S  = (u16*)(ws + 140509184);            // 8 x 2048x2048 bf16= 64 MiB
    // total 207,618,048 bytes

    // 1) casts
    cast_f32_bf16<<<16384, 256, 0, stream>>>((const float4*)x, (ushort4*)xb, 4194304);
    dim3 tg(32, 32), tb(32, 8);
    transpose_cast<<<tg, tb, 0, stream>>>(Wq, WT);
    transpose_cast<<<tg, tb, 0, stream>>>(Wk, WT + 1048576);
    transpose_cast<<<tg, tb, 0, stream>>>(Wv, WT + 2097152);

    // 2) fused QKV projection: [16384,3072] = xb @ WT^T + b
    dim3 gp(24, 128, 1);
    gemm_bt<0><<<gp, 256, 0, stream>>>(xb, 1024, 0, WT, 1024, 0,
                                       bq, bk, bv, QK, Vt, 0, 0, 1024, 1.0f);

    // 3) scores S[b] = (Q[b] @ K[b]^T) / 32, bf16
    dim3 gs(16, 16, 8);
    gemm_bt<2><<<gs, 256, 0, stream>>>(QK, 2048, 2048L * 2048, QK + 1024, 2048, 2048L * 2048,
                                       nullptr, nullptr, nullptr, S, nullptr,
                                       2048, 2048L * 2048, 1024, 0.03125f);

    // 4) row softmax in place
    softmax_rows<<<16384, 256, 0, stream>>>(S);

    // 5) out[b] = P[b] @ V[b]   (via Vt, fp32 out)
    dim3 gv(8, 16, 8);
    gemm_bt<3><<<gv, 256, 0, stream>>>(S, 2048, 2048L * 2048, Vt, 2048, 1024L * 2048,
                                       nullptr, nullptr, nullptr, out, nullptr,
                                       1024, 2048L * 1024, 2048, 1.0f);
}

// Round 4
// 428.015 us; speedup vs baseline: 1.3283x; 1.1066x over previous
//
#include <hip/hip_runtime.h>
#include <hip/hip_bf16.h>

typedef unsigned short u16;
typedef short bf16x8 __attribute__((ext_vector_type(8)));
typedef float f32x16 __attribute__((ext_vector_type(16)));
typedef unsigned short u16x8 __attribute__((ext_vector_type(8)));
typedef unsigned short u16x4 __attribute__((ext_vector_type(4)));

__device__ __forceinline__ u16 f2bf(float f) {
    unsigned u = __float_as_uint(f);
    return (u16)((u + 0x7FFFu + ((u >> 16) & 1u)) >> 16);  // RNE, no NaNs here
}
__device__ __forceinline__ float bf2f(u16 h) {
    return __uint_as_float(((unsigned)h) << 16);
}

// ---------------------------------------------------------------------------
// Elementwise fp32 -> bf16 cast (x). n4 = elements/4.
// ---------------------------------------------------------------------------
__global__ __launch_bounds__(256) void cast_f32_bf16(const float4* __restrict__ src,
                                                     ushort4* __restrict__ dst, int n4) {
    int i = blockIdx.x * 256 + threadIdx.x;
    if (i < n4) {
        float4 v = src[i];
        ushort4 o;
        o.x = f2bf(v.x); o.y = f2bf(v.y); o.z = f2bf(v.z); o.w = f2bf(v.w);
        dst[i] = o;
    }
}

// ---------------------------------------------------------------------------
// 3x 1024x1024 fp32 -> bf16 transpose in one dispatch (z selects weight)
// ---------------------------------------------------------------------------
__global__ __launch_bounds__(256) void transpose_cast3(const float* __restrict__ W0,
                                                       const float* __restrict__ W1,
                                                       const float* __restrict__ W2,
                                                       u16* __restrict__ WT) {
    __shared__ float t[32][33];
    const float* W = (blockIdx.z == 0) ? W0 : (blockIdx.z == 1) ? W1 : W2;
    u16* Wt = WT + (long)blockIdx.z * 1048576;
    int bx = blockIdx.x * 32;  // n
    int by = blockIdx.y * 32;  // k
    int tx = threadIdx.x, ty = threadIdx.y;
    for (int r = ty; r < 32; r += 8)
        t[r][tx] = W[(by + r) * 1024 + bx + tx];
    __syncthreads();
    for (int r = ty; r < 32; r += 8)
        Wt[(long)(bx + r) * 1024 + by + tx] = f2bf(t[tx][r]);
}

// ---------------------------------------------------------------------------
// 128x128-tile bf16 MFMA GEMM, B^T input form: C = A[M,K] * Bt[N,K]^T
// 256 threads = 4 waves (2x2 of 64x64), each wave 2x2 tiles of 32x32x16.
// BK=64: LDS row = 128 B = one L2 line; bank swizzle is line-local
// (chunk slot = kc ^ (row&7)), so staging is perfectly line-coalesced and
// fragment reads spread 8 bank-groups x 4 lanes.
// MODE 0: fused QKV projection. cols<2048 -> bf16+bias into QK[16384][2048];
//         cols>=2048 -> bf16+bias TRANSPOSED into Vt[b][1024][2048].
// MODE 2: bf16 out * scale (scores)
// MODE 3: fp32 out (attn @ V -> d_out)
// ---------------------------------------------------------------------------
template <int MODE>
__global__ __launch_bounds__(256)
void gemm_bt(const u16* __restrict__ A, int lda, long sA,
             const u16* __restrict__ Bt, int ldb, long sB,
             const float* __restrict__ bq_, const float* __restrict__ bk_,
             const float* __restrict__ bv_,
             void* __restrict__ Cout, void* __restrict__ Cout2,
             int ldc, long sC, int Kdim, float scale)
{
    __shared__ __align__(16) u16 As[128 * 64];
    __shared__ __align__(16) u16 Bs[128 * 64];
    const int tid  = threadIdx.x;
    const int wave = tid >> 6;
    const int lane = tid & 63;
    const int m32  = lane & 31;
    const int hi   = lane >> 5;

    // XCD swizzle: flat%8 -> XCD; give each XCD a contiguous tile span.
    const int gx = gridDim.x, gy = gridDim.y;
    int flat = (blockIdx.z * gy + blockIdx.y) * gx + blockIdx.x;
    int total = gx * gy * gridDim.z;
    int tile = (flat & 7) * (total >> 3) + (flat >> 3);
    const int bx = tile % gx;
    const int by = (tile / gx) % gy;
    const int bz = tile / (gx * gy);

    const u16* Ab = A + (long)bz * sA;
    const u16* Bb = Bt + (long)bz * sB;
    const int row0 = by * 128;
    const int col0 = bx * 128;
    const int wr = (wave & 1) * 64;
    const int wc = (wave >> 1) * 64;

    f32x16 acc[2][2] = {};

    // per-lane fragment rows and line-local swizzle keys
    int arow[2], brow[2], asw[2], bsw[2];
#pragma unroll
    for (int t = 0; t < 2; ++t) {
        arow[t] = wr + t * 32 + m32;
        brow[t] = wc + t * 32 + m32;
        asw[t] = arow[t] & 7;
        bsw[t] = brow[t] & 7;
    }

    for (int k0 = 0; k0 < Kdim; k0 += 64) {
        // stage A/B 128x64 tiles: 1024 16B-chunks each, 4/thread/tile.
        // slot s=c&7 of row r holds chunk kc = s ^ (r&7) (within one 128B line).
#pragma unroll
        for (int it = 0; it < 4; ++it) {
            int c = it * 256 + tid;
            int r = c >> 3;
            int kc = (c & 7) ^ (r & 7);
            const u16* ga = Ab + (long)(row0 + r) * lda + (k0 + kc * 8);
            __builtin_amdgcn_global_load_lds(
                (const __attribute__((address_space(1))) void*)ga,
                (__attribute__((address_space(3))) void*)(&As[c * 8]), 16, 0, 0);
            const u16* gb = Bb + (long)(col0 + r) * ldb + (k0 + kc * 8);
            __builtin_amdgcn_global_load_lds(
                (const __attribute__((address_space(1))) void*)gb,
                (__attribute__((address_space(3))) void*)(&Bs[c * 8]), 16, 0, 0);
        }
        __syncthreads();
        // fragment: A[m=lane&31][k=kh*16 + hi*8 + j] -> chunk q = kh*2+hi
#pragma unroll
        for (int kh = 0; kh < 4; ++kh) {
            bf16x8 af[2], bfr[2];
#pragma unroll
            for (int t = 0; t < 2; ++t) {
                int qa = (kh * 2 + hi) ^ asw[t];
                int qb = (kh * 2 + hi) ^ bsw[t];
                af[t]  = *(const bf16x8*)&As[arow[t] * 64 + qa * 8];
                bfr[t] = *(const bf16x8*)&Bs[brow[t] * 64 + qb * 8];
            }
#pragma unroll
            for (int i = 0; i < 2; ++i)
#pragma unroll
                for (int j = 0; j < 2; ++j)
                    acc[i][j] = __builtin_amdgcn_mfma_f32_32x32x16_bf16(
                        af[i], bfr[j], acc[i][j], 0, 0, 0);
        }
        __syncthreads();
    }

    // epilogue: 32x32 C/D layout col=lane&31, row=(reg&3)+8*(reg>>2)+4*(lane>>5)
    if (MODE == 0) {
        if (col0 < 2048) {
            const float* bp = (col0 < 1024) ? bq_ : bk_;
#pragma unroll
            for (int i = 0; i < 2; ++i) {
#pragma unroll
                for (int j = 0; j < 2; ++j) {
                    int col = col0 + wc + j * 32 + m32;
                    float badd = bp[col & 1023];
#pragma unroll
                    for (int g = 0; g < 4; ++g) {
                        int rbase = row0 + wr + i * 32 + 4 * hi + 8 * g;
#pragma unroll
                        for (int rr = 0; rr < 4; ++rr)
                            ((u16*)Cout)[(long)(rbase + rr) * 2048 + col] =
                                f2bf(acc[i][j][g * 4 + rr] + badd);
                    }
                }
            }
        } else {
            // V part: store transposed into Vt[b][1024][2048], 4 rows packed
#pragma unroll
            for (int i = 0; i < 2; ++i) {
#pragma unroll
                for (int j = 0; j < 2; ++j) {
                    int d = col0 + wc + j * 32 + m32 - 2048;
                    float badd = bv_[d];
#pragma unroll
                    for (int g = 0; g < 4; ++g) {
                        int rbase = row0 + wr + i * 32 + 4 * hi + 8 * g;
                        int b = rbase >> 11, m = rbase & 2047;
                        u16x4 pk;
#pragma unroll
                        for (int rr = 0; rr < 4; ++rr)
                            pk[rr] = f2bf(acc[i][j][g * 4 + rr] + badd);
                        *(u16x4*)((u16*)Cout2 + ((long)b << 21) + ((long)d << 11) + m) = pk;
                    }
                }
            }
        }
    } else {
#pragma unroll
        for (int i = 0; i < 2; ++i) {
#pragma unroll
            for (int j = 0; j < 2; ++j) {
                int col = col0 + wc + j * 32 + m32;
#pragma unroll
                for (int g = 0; g < 4; ++g) {
                    int rbase = row0 + wr + i * 32 + 4 * hi + 8 * g;
#pragma unroll
                    for (int rr = 0; rr < 4; ++rr) {
                        int row = rbase + rr;
                        float v = acc[i][j][g * 4 + rr];
                        if (MODE == 2) {
                            ((u16*)Cout)[(long)bz * sC + (long)row * ldc + col] = f2bf(v * scale);
                        } else {
                            ((float*)Cout)[(long)bz * sC + (long)row * ldc + col] = v;
                        }
                    }
                }
            }
        }
    }
}

// ---------------------------------------------------------------------------
// In-place row softmax over bf16 [16384 rows][2048], one block per row.
// ---------------------------------------------------------------------------
__global__ __launch_bounds__(256) void softmax_rows(u16* __restrict__ S) {
    __shared__ float red[4];
    const long row = blockIdx.x;
    u16* p = S + row * 2048;
    const int tid = threadIdx.x;
    const int lane = tid & 63, wv = tid >> 6;

    u16x8 raw = *(const u16x8*)(p + tid * 8);
    float v[8];
#pragma unroll
    for (int i = 0; i < 8; ++i) v[i] = bf2f(raw[i]);

    float m = -1e30f;
#pragma unroll
    for (int i = 0; i < 8; ++i) m = fmaxf(m, v[i]);
    for (int off = 32; off > 0; off >>= 1) m = fmaxf(m, __shfl_down(m, off));
    if (lane == 0) red[wv] = m;
    __syncthreads();
    m = fmaxf(fmaxf(red[0], red[1]), fmaxf(red[2], red[3]));

    float s = 0.0f;
#pragma unroll
    for (int i = 0; i < 8; ++i) { v[i] = __expf(v[i] - m); s += v[i]; }
    for (int off = 32; off > 0; off >>= 1) s += __shfl_down(s, off);
    __syncthreads();
    if (lane == 0) red[wv] = s;
    __syncthreads();
    s = red[0] + red[1] + red[2] + red[3];
    float inv = 1.0f / s;

    u16x8 o;
#pragma unroll
    for (int i = 0; i < 8; ++i) o[i] = f2bf(v[i] * inv);
    *(u16x8*)(p + tid * 8) = o;
}

// ---------------------------------------------------------------------------
extern "C" void kernel_launch(void* const* d_in, const int* in_sizes, int n_in,
                              void* d_out, int out_size, void* d_ws, size_t ws_size,
                              hipStream_t stream) {
    const float* x  = (const float*)d_in[0];
    const float* Wq = (const float*)d_in[1];
    const float* bq = (const float*)d_in[2];
    const float* Wk = (const float*)d_in[3];
    const float* bk = (const float*)d_in[4];
    const float* Wv = (const float*)d_in[5];
    const float* bv = (const float*)d_in[6];
    float* out = (float*)d_out;

    // workspace layout (bytes)
    char* ws = (char*)d_ws;
    u16* xb = (u16*)(ws);                        // 16384x1024 bf16   = 32 MiB
    u16* WT = (u16*)(ws + 33554432);             // 3072x1024 bf16    =  6 MiB
    u16* QK = (u16*)(ws + 39845888);             // 16384x2048 bf16   = 64 MiB
    u16* Vt = (u16*)(ws + 106954752);            // 8 x 1024x2048 bf16= 32 MiB
    u16* S  = (u16*)(ws + 140509184);            // 8 x 2048x2048 bf16= 64 MiB
    // total 207,618,048 bytes

    // 1) casts
    cast_f32_bf16<<<16384, 256, 0, stream>>>((const float4*)x, (ushort4*)xb, 4194304);
    dim3 tg(32, 32, 3), tb(32, 8);
    transpose_cast3<<<tg, tb, 0, stream>>>(Wq, Wk, Wv, WT);

    // 2) fused QKV projection: [16384,3072] = xb @ WT^T + b
    dim3 gp(24, 128, 1);
    gemm_bt<0><<<gp, 256, 0, stream>>>(xb, 1024, 0, WT, 1024, 0,
                                       bq, bk, bv, QK, Vt, 0, 0, 1024, 1.0f);

    // 3) scores S[b] = (Q[b] @ K[b]^T) / 32, bf16
    dim3 gs(16, 16, 8);
    gemm_bt<2><<<gs, 256, 0, stream>>>(QK, 2048, 2048L * 2048, QK + 1024, 2048, 2048L * 2048,
                                       nullptr, nullptr, nullptr, S, nullptr,
                                       2048, 2048L * 2048, 1024, 0.03125f);

    // 4) row softmax in place
    softmax_rows<<<16384, 256, 0, stream>>>(S);

    // 5) out[b] = P[b] @ V[b]   (via Vt, fp32 out)
    dim3 gv(8, 16, 8);
    gemm_bt<3><<<gv, 256, 0, stream>>>(S, 2048, 2048L * 2048, Vt, 2048, 1024L * 2048,
                                       nullptr, nullptr, nullptr, out, nullptr,
                                       1024, 2048L * 1024, 2048, 1.0f);
}